// Round 2
// baseline (167.272 us; speedup 1.0000x reference)
//
#include <hip/hip_runtime.h>
#include <hip/hip_bf16.h>
#include <cstdint>
#include <cstddef>

#define HDIM 512
#define NEXP 8

typedef __bf16 bf16t;
typedef __attribute__((ext_vector_type(8))) __bf16 bf16x8;
typedef __attribute__((ext_vector_type(4))) __bf16 bf16x4;
typedef __attribute__((ext_vector_type(4))) float f32x4;

__device__ inline void gload_lds16(const void* g, void* l) {
  __builtin_amdgcn_global_load_lds(
      (const __attribute__((address_space(1))) void*)g,
      (__attribute__((address_space(3))) void*)l, 16, 0, 0);
}

// ---------------- zero output ----------------
__global__ void k_zero(float4* __restrict__ p, int n4) {
  int i = blockIdx.x * blockDim.x + threadIdx.x;
  int st = gridDim.x * blockDim.x;
  for (; i < n4; i += st) p[i] = make_float4(0.f, 0.f, 0.f, 0.f);
}

// ---------------- init counters ----------------
__global__ void k_init(int* __restrict__ counts) {
  if (threadIdx.x < NEXP) counts[threadIdx.x] = 0;
}

// ---------------- W[e][h][o] f32 -> wT[e][o][h] bf16 (transpose+convert) ----
__global__ void k_wt(const float* __restrict__ W, bf16t* __restrict__ wT) {
  __shared__ float t[64][65];
  int b = blockIdx.x;
  int e = b >> 6, ht = (b >> 3) & 7, ot = b & 7;
  const float* We = W + (size_t)e * HDIM * HDIM;
  int tid = threadIdx.x;
  int c = tid & 63, rr = tid >> 6;  // 4 rows per pass
#pragma unroll
  for (int i = 0; i < 16; ++i) {
    int h = i * 4 + rr;
    t[h][c] = We[(size_t)(ht * 64 + h) * HDIM + ot * 64 + c];
  }
  __syncthreads();
  bf16t* dst = wT + (size_t)e * HDIM * HDIM;
#pragma unroll
  for (int i = 0; i < 16; ++i) {
    int o = i * 4 + rr;
    dst[(size_t)(ot * 64 + o) * HDIM + ht * 64 + c] = (bf16t)t[c][o];
  }
}

// ---------------- router: logits fp32, softmax, top-2, counts; + x->bf16 ----
__global__ void k_router(const float* __restrict__ x, const float* __restrict__ rw,
                         int* __restrict__ idx0, int* __restrict__ idx1,
                         float* __restrict__ w0, float* __restrict__ w1,
                         int* __restrict__ counts, bf16t* __restrict__ xb,
                         int useXB, int ntok) {
  __shared__ int lcnt[NEXP];
  int tid = threadIdx.x;
  if (tid < NEXP) lcnt[tid] = 0;
  __syncthreads();
  int wv = tid >> 6, lane = tid & 63;
  int g = lane >> 3, r = lane & 7;  // expert group, lane-in-group
  const float4* wrow = (const float4*)(rw + g * HDIM);
  for (int it = 0; it < 8; ++it) {
    int n = blockIdx.x * 32 + wv * 8 + it;
    if (n >= ntok) break;
    const float4* xrow = (const float4*)(x + (size_t)n * HDIM);
    float acc = 0.f;
#pragma unroll
    for (int t = 0; t < 16; ++t) {
      float4 xv = xrow[t * 8 + r];
      float4 wvv = wrow[t * 8 + r];
      acc += xv.x * wvv.x + xv.y * wvv.y + xv.z * wvv.z + xv.w * wvv.w;
    }
    acc += __shfl_xor(acc, 1);
    acc += __shfl_xor(acc, 2);
    acc += __shfl_xor(acc, 4);  // every lane of group g now has logit[g]
    float lg[NEXP];
#pragma unroll
    for (int e = 0; e < NEXP; ++e) lg[e] = __shfl(acc, e * 8);
    float m = lg[0];
#pragma unroll
    for (int e = 1; e < NEXP; ++e) m = fmaxf(m, lg[e]);
    float p[NEXP];
    float S = 0.f;
#pragma unroll
    for (int e = 0; e < NEXP; ++e) { p[e] = expf(lg[e] - m); S += p[e]; }
    float inv = 1.f / S;
#pragma unroll
    for (int e = 0; e < NEXP; ++e) p[e] *= inv;
    // top-2 with lowest-index tie-break (strict >)
    int b0 = 0;
#pragma unroll
    for (int e = 1; e < NEXP; ++e) if (p[e] > p[b0]) b0 = e;
    int b1 = (b0 == 0) ? 1 : 0;
#pragma unroll
    for (int e = 0; e < NEXP; ++e) if (e != b0 && p[e] > p[b1]) b1 = e;
    float v0 = p[b0], v1 = p[b1];
    float s = v0 + v1 + 1e-6f;
    if (lane == 0) {
      idx0[n] = b0; idx1[n] = b1;
      w0[n] = v0 / s; w1[n] = v1 / s;
      atomicAdd(&lcnt[b0], 1);
      atomicAdd(&lcnt[b1], 1);
    }
  }
  __syncthreads();
  if (tid < NEXP && lcnt[tid] > 0) atomicAdd(&counts[tid], lcnt[tid]);
  // fused x -> bf16 conversion for this block's 32 tokens
  if (useXB) {
    int base = blockIdx.x * 32;
    int nrem = ntok - base;
    if (nrem > 0) {
      if (nrem > 32) nrem = 32;
      const float4* src = (const float4*)(x + (size_t)base * HDIM);
      bf16x4* dst = (bf16x4*)(xb + (size_t)base * HDIM);
      int tot4 = nrem * (HDIM / 4);
      for (int i = tid; i < tot4; i += 256) {
        float4 v = src[i];
        bf16x4 h;
        h[0] = (bf16t)v.x; h[1] = (bf16t)v.y; h[2] = (bf16t)v.z; h[3] = (bf16t)v.w;
        dst[i] = h;
      }
    }
  }
}

// ------- offsets + exact tile list (ntiles <= 2*ntok/128 + NEXP-1) ----------
__global__ void k_offsets(const int* __restrict__ counts, int* __restrict__ offs,
                          int* __restrict__ cursor, int* __restrict__ ntiles,
                          int* __restrict__ tlist) {
  if (threadIdx.x == 0) {
    int s = 0, nt = 0;
    for (int e = 0; e < NEXP; ++e) {
      offs[e] = s; cursor[e] = s;
      int c = counts[e];
      s += c;
      int rtn = (c + 127) >> 7;
      for (int r = 0; r < rtn; ++r) tlist[nt++] = (e << 16) | r;
    }
    ntiles[0] = nt;
  }
}

// ---------------- scatter tokens into per-expert buckets --------------------
__global__ void k_scatter(const int* __restrict__ idx0, const int* __restrict__ idx1,
                          const float* __restrict__ w0, const float* __restrict__ w1,
                          int* __restrict__ cursor, int* __restrict__ btok,
                          float* __restrict__ bw, int ntok) {
  __shared__ int lcnt[NEXP], lbase[NEXP];
  int tid = threadIdx.x;
  if (tid < NEXP) lcnt[tid] = 0;
  __syncthreads();
  int n = blockIdx.x * 64 + tid;
  int e0 = 0, e1 = 0, p0 = 0, p1 = 0;
  float a0 = 0.f, a1 = 0.f;
  bool act = (n < ntok);
  if (act) {
    e0 = idx0[n]; e1 = idx1[n]; a0 = w0[n]; a1 = w1[n];
    p0 = atomicAdd(&lcnt[e0], 1);
    p1 = atomicAdd(&lcnt[e1], 1);
  }
  __syncthreads();
  if (tid < NEXP) lbase[tid] = lcnt[tid] ? atomicAdd(&cursor[tid], lcnt[tid]) : 0;
  __syncthreads();
  if (act) {
    int q0 = lbase[e0] + p0; btok[q0] = n; bw[q0] = a0;
    int q1 = lbase[e1] + p1; btok[q1] = n; bw[q1] = a1;
  }
}

// ---------------- grouped GEMM over exact tile list -------------------------
// Tile 128x128, BK=32, 4 waves (2x2), mfma_f32_16x16x32_bf16.
// XB=true : A gathered from xb (bf16) via global_load_lds 16B (fast path).
// XB=false: A gathered from x (f32) via reg staging + convert (ws fallback).
template <bool XB>
__global__ __launch_bounds__(256, 4) void k_gemm(
    const float* __restrict__ x, const bf16t* __restrict__ xb,
    const bf16t* __restrict__ wT, const int* __restrict__ btok,
    const float* __restrict__ bw, const int* __restrict__ counts,
    const int* __restrict__ offs, const int* __restrict__ ntiles,
    const int* __restrict__ tlist, float* __restrict__ out) {
  __shared__ bf16t Asm[128 * 32];  // [row][k] 8KB
  __shared__ bf16t Bsm[128 * 32];  // [n][k]   8KB
  int bid = blockIdx.x;
  int t = bid >> 2, ct = bid & 3;
  if (t >= ntiles[0]) return;
  int pk = tlist[t];
  int e = pk >> 16, rt = pk & 0xffff;
  int cnt = counts[e], off = offs[e];
  int m0 = rt << 7, n0 = ct << 7;
  int tid = threadIdx.x;
  int lane = tid & 63;
  int wv = tid >> 6, wr = wv >> 1, wc = wv & 1;

  // B staging: 2 issues x (64 rows, 16B per thread)
  const bf16t* bsrc[2];
  {
    int rr = tid >> 2, chk = tid & 3;
#pragma unroll
    for (int i = 0; i < 2; ++i)
      bsrc[i] = wT + (size_t)(e * HDIM + n0 + i * 64 + rr) * HDIM + chk * 8;
  }
  // A staging
  const bf16t* asrcb[2];
  const float* asrcf[4];
  int aldsoff[4];
  if (XB) {
    int rr = tid >> 2, chk = tid & 3;
#pragma unroll
    for (int i = 0; i < 2; ++i) {
      int gr = m0 + i * 64 + rr;
      if (gr > cnt - 1) gr = cnt - 1;  // clamp ragged tail (stores guarded)
      int tok = btok[off + gr];
      asrcb[i] = xb + (size_t)tok * HDIM + chk * 8;
    }
  } else {
    int rr = tid >> 3, chk = tid & 7;
#pragma unroll
    for (int i = 0; i < 4; ++i) {
      int gr = m0 + i * 32 + rr;
      if (gr > cnt - 1) gr = cnt - 1;
      int tok = btok[off + gr];
      asrcf[i] = x + (size_t)tok * HDIM + chk * 4;
      aldsoff[i] = (i * 32 + rr) * 32 + chk * 4;
    }
  }

  f32x4 acc[4][4];
#pragma unroll
  for (int a = 0; a < 4; ++a)
#pragma unroll
    for (int b = 0; b < 4; ++b) acc[a][b] = f32x4{0.f, 0.f, 0.f, 0.f};

  int aro = (wr * 64 + (lane & 15)) * 32 + (lane >> 4) * 8;
  int bro = (wc * 64 + (lane & 15)) * 32 + (lane >> 4) * 8;

  for (int kt = 0; kt < HDIM / 32; ++kt) {
    int k0 = kt * 32;
#pragma unroll
    for (int i = 0; i < 2; ++i)
      gload_lds16(bsrc[i] + k0, Bsm + i * 2048 + tid * 8);
    if (XB) {
#pragma unroll
      for (int i = 0; i < 2; ++i)
        gload_lds16(asrcb[i] + k0, Asm + i * 2048 + tid * 8);
    } else {
#pragma unroll
      for (int i = 0; i < 4; ++i) {
        float4 v = *(const float4*)(asrcf[i] + k0);
        bf16x4 h;
        h[0] = (bf16t)v.x; h[1] = (bf16t)v.y; h[2] = (bf16t)v.z; h[3] = (bf16t)v.w;
        *(bf16x4*)(Asm + aldsoff[i]) = h;
      }
    }
    __syncthreads();  // drains vmcnt (global_load_lds) + lgkm (ds_write)
    bf16x8 af[4], bfr[4];
#pragma unroll
    for (int mi = 0; mi < 4; ++mi)
      af[mi] = *(const bf16x8*)(Asm + aro + mi * 16 * 32);
#pragma unroll
    for (int ni = 0; ni < 4; ++ni)
      bfr[ni] = *(const bf16x8*)(Bsm + bro + ni * 16 * 32);
#pragma unroll
    for (int mi = 0; mi < 4; ++mi)
#pragma unroll
      for (int ni = 0; ni < 4; ++ni)
        acc[mi][ni] =
            __builtin_amdgcn_mfma_f32_16x16x32_bf16(af[mi], bfr[ni], acc[mi][ni], 0, 0, 0);
    __syncthreads();
  }

  // Epilogue: D[row][col]: col = lane&15, row = (lane>>4)*4 + j  [m89/m91]
  int col0 = n0 + wc * 64 + (lane & 15);
  int rbase = m0 + wr * 64 + ((lane >> 4) << 2);
#pragma unroll
  for (int mi = 0; mi < 4; ++mi) {
#pragma unroll
    for (int j = 0; j < 4; ++j) {
      int rrow = rbase + mi * 16 + j;
      if (rrow < cnt) {
        int tok = btok[off + rrow];
        float w = bw[off + rrow];
        float* orow = out + (size_t)tok * HDIM + col0;
#pragma unroll
        for (int ni = 0; ni < 4; ++ni)
          atomicAdd(orow + ni * 16, w * acc[mi][ni][j]);
      }
    }
  }
}

extern "C" void kernel_launch(void* const* d_in, const int* in_sizes, int n_in,
                              void* d_out, int out_size, void* d_ws, size_t ws_size,
                              hipStream_t stream) {
  const float* x = (const float*)d_in[0];
  const float* rw = (const float*)d_in[1];
  const float* W = (const float*)d_in[2];
  float* out = (float*)d_out;
  int ntok = in_sizes[0] / HDIM;  // 16384 for B=4,S=4096
  if (ntok <= 0) return;
  int maxT = ((2 * ntok + 127) >> 7) + NEXP - 1;  // exact worst-case tile count

  // workspace layout
  char* ws = (char*)d_ws;
  size_t o = 0;
  bf16t* wT = (bf16t*)(ws + o); o += (size_t)NEXP * HDIM * HDIM * sizeof(bf16t);
  int* idx0 = (int*)(ws + o); o += (size_t)ntok * 4;
  int* idx1 = (int*)(ws + o); o += (size_t)ntok * 4;
  float* w0 = (float*)(ws + o); o += (size_t)ntok * 4;
  float* w1 = (float*)(ws + o); o += (size_t)ntok * 4;
  int* meta = (int*)(ws + o); o += 256;   // counts[8], offs[8], cursor[8], ntiles
  int* counts = meta;
  int* offs = meta + 8;
  int* cursor = meta + 16;
  int* ntiles = meta + 24;
  int* tlist = (int*)(ws + o); o += (size_t)((maxT * 4 + 255) & ~255);
  int* btok = (int*)(ws + o); o += (size_t)2 * ntok * 4;
  float* bw = (float*)(ws + o); o += (size_t)2 * ntok * 4;
  size_t oBase = o;
  bf16t* xb = (bf16t*)(ws + o); o += (size_t)ntok * HDIM * sizeof(bf16t);
  if (ws_size < oBase) return;            // ~5 MB minimum
  int useXB = (ws_size >= o) ? 1 : 0;     // +16.8 MB fast path

  k_init<<<dim3(1), dim3(64), 0, stream>>>(counts);
  k_wt<<<dim3(512), dim3(256), 0, stream>>>(W, wT);
  k_router<<<dim3((ntok + 31) / 32), dim3(256), 0, stream>>>(x, rw, idx0, idx1, w0, w1,
                                                             counts, xb, useXB, ntok);
  k_offsets<<<dim3(1), dim3(64), 0, stream>>>(counts, offs, cursor, ntiles, tlist);
  k_scatter<<<dim3((ntok + 63) / 64), dim3(64), 0, stream>>>(idx0, idx1, w0, w1, cursor,
                                                             btok, bw, ntok);
  k_zero<<<dim3(2048), dim3(256), 0, stream>>>((float4*)out, ntok * HDIM / 4);
  if (useXB)
    k_gemm<true><<<dim3(maxT * 4), dim3(256), 0, stream>>>(x, xb, wT, btok, bw, counts,
                                                           offs, ntiles, tlist, out);
  else
    k_gemm<false><<<dim3(maxT * 4), dim3(256), 0, stream>>>(x, xb, wT, btok, bw, counts,
                                                            offs, ntiles, tlist, out);
}

// Round 3
// 126.350 us; speedup vs baseline: 1.3239x; 1.3239x over previous
//
#include <hip/hip_runtime.h>
#include <hip/hip_bf16.h>
#include <cstdint>
#include <cstddef>

#define HDIM 512
#define NEXP 8

typedef __bf16 bf16t;
typedef __attribute__((ext_vector_type(8))) __bf16 bf16x8;
typedef __attribute__((ext_vector_type(4))) __bf16 bf16x4;
typedef __attribute__((ext_vector_type(4))) float f32x4;

__device__ inline void gload_lds16(const void* g, void* l) {
  __builtin_amdgcn_global_load_lds(
      (const __attribute__((address_space(1))) void*)g,
      (__attribute__((address_space(3))) void*)l, 16, 0, 0);
}

// ---------------- zero output (fallback path only) ----------------
__global__ void k_zero(float4* __restrict__ p, int n4) {
  int i = blockIdx.x * blockDim.x + threadIdx.x;
  int st = gridDim.x * blockDim.x;
  for (; i < n4; i += st) p[i] = make_float4(0.f, 0.f, 0.f, 0.f);
}

// -------- W[e][h][o] f32 -> wT[e][o][h] bf16 (transpose+convert) + init ----
__global__ void k_wt(const float* __restrict__ W, bf16t* __restrict__ wT,
                     int* __restrict__ counts) {
  if (blockIdx.x == 0 && threadIdx.x < NEXP) counts[threadIdx.x] = 0;
  __shared__ float t[64][65];
  int b = blockIdx.x;
  int e = b >> 6, ht = (b >> 3) & 7, ot = b & 7;
  const float* We = W + (size_t)e * HDIM * HDIM;
  int tid = threadIdx.x;
  int c = tid & 63, rr = tid >> 6;
#pragma unroll
  for (int i = 0; i < 16; ++i) {
    int h = i * 4 + rr;
    t[h][c] = We[(size_t)(ht * 64 + h) * HDIM + ot * 64 + c];
  }
  __syncthreads();
  bf16t* dst = wT + (size_t)e * HDIM * HDIM;
#pragma unroll
  for (int i = 0; i < 16; ++i) {
    int o = i * 4 + rr;
    dst[(size_t)(ot * 64 + o) * HDIM + ht * 64 + c] = (bf16t)t[c][o];
  }
}

// ---- router: one wave per token, x read ONCE, fused x->bf16 conversion ----
__global__ void k_router(const float* __restrict__ x, const float* __restrict__ rw,
                         int* __restrict__ idx0, int* __restrict__ idx1,
                         float* __restrict__ w0, float* __restrict__ w1,
                         int* __restrict__ counts, bf16t* __restrict__ xb,
                         int ntok) {
  __shared__ int lcnt[NEXP];
  int tid = threadIdx.x;
  if (tid < NEXP) lcnt[tid] = 0;
  __syncthreads();
  int lane = tid & 63;
  int gw = (blockIdx.x * blockDim.x + tid) >> 6;
  int nw = (gridDim.x * blockDim.x) >> 6;
  // per-lane slice of all 8 expert rows: rw[e][lane*8 .. +7]
  float4 rv[NEXP][2];
#pragma unroll
  for (int e = 0; e < NEXP; ++e) {
    const float4* p = (const float4*)(rw + e * HDIM + lane * 8);
    rv[e][0] = p[0]; rv[e][1] = p[1];
  }
  for (int n = gw; n < ntok; n += nw) {
    const float4* xr = (const float4*)(x + (size_t)n * HDIM + lane * 8);
    float4 xv0 = xr[0], xv1 = xr[1];
    float a[NEXP];
#pragma unroll
    for (int e = 0; e < NEXP; ++e) {
      a[e] = xv0.x * rv[e][0].x + xv0.y * rv[e][0].y + xv0.z * rv[e][0].z +
             xv0.w * rv[e][0].w + xv1.x * rv[e][1].x + xv1.y * rv[e][1].y +
             xv1.z * rv[e][1].z + xv1.w * rv[e][1].w;
    }
#pragma unroll
    for (int s = 1; s < 64; s <<= 1) {
#pragma unroll
      for (int e = 0; e < NEXP; ++e) a[e] += __shfl_xor(a[e], s);
    }
    // softmax + top-2 (computed redundantly by all lanes; lane 0 writes)
    float m = a[0];
#pragma unroll
    for (int e = 1; e < NEXP; ++e) m = fmaxf(m, a[e]);
    float p[NEXP], S = 0.f;
#pragma unroll
    for (int e = 0; e < NEXP; ++e) { p[e] = expf(a[e] - m); S += p[e]; }
    float inv = 1.f / S;
#pragma unroll
    for (int e = 0; e < NEXP; ++e) p[e] *= inv;
    int b0 = 0;
#pragma unroll
    for (int e = 1; e < NEXP; ++e) if (p[e] > p[b0]) b0 = e;
    int b1 = (b0 == 0) ? 1 : 0;
#pragma unroll
    for (int e = 0; e < NEXP; ++e) if (e != b0 && p[e] > p[b1]) b1 = e;
    float v0 = p[b0], v1 = p[b1];
    float s = v0 + v1 + 1e-6f;
    if (lane == 0) {
      idx0[n] = b0; idx1[n] = b1;
      w0[n] = v0 / s; w1[n] = v1 / s;
      atomicAdd(&lcnt[b0], 1);
      atomicAdd(&lcnt[b1], 1);
    }
    // fused bf16 conversion from already-loaded registers
    bf16x8 h;
    h[0] = (bf16t)xv0.x; h[1] = (bf16t)xv0.y; h[2] = (bf16t)xv0.z; h[3] = (bf16t)xv0.w;
    h[4] = (bf16t)xv1.x; h[5] = (bf16t)xv1.y; h[6] = (bf16t)xv1.z; h[7] = (bf16t)xv1.w;
    *(bf16x8*)(xb + (size_t)n * HDIM + lane * 8) = h;
  }
  __syncthreads();
  if (tid < NEXP && lcnt[tid] > 0) atomicAdd(&counts[tid], lcnt[tid]);
}

// ------- offsets + exact tile list (ntiles <= 2*ntok/128 + NEXP-1) ----------
__global__ void k_offsets(const int* __restrict__ counts, int* __restrict__ offs,
                          int* __restrict__ cursor, int* __restrict__ ntiles,
                          int* __restrict__ tlist) {
  if (threadIdx.x == 0) {
    int s = 0, nt = 0;
    for (int e = 0; e < NEXP; ++e) {
      offs[e] = s; cursor[e] = s;
      int c = counts[e];
      s += c;
      int rtn = (c + 127) >> 7;
      for (int r = 0; r < rtn; ++r) tlist[nt++] = (e << 16) | r;
    }
    ntiles[0] = nt;
  }
}

// ---- scatter tokens into per-expert buckets; record inverse positions ----
__global__ void k_scatter(const int* __restrict__ idx0, const int* __restrict__ idx1,
                          const float* __restrict__ w0, const float* __restrict__ w1,
                          int* __restrict__ cursor, int* __restrict__ btok,
                          float* __restrict__ bw, int* __restrict__ pos0,
                          int* __restrict__ pos1, int ntok) {
  __shared__ int lcnt[NEXP], lbase[NEXP];
  int tid = threadIdx.x;
  if (tid < NEXP) lcnt[tid] = 0;
  __syncthreads();
  int n = blockIdx.x * 64 + tid;
  int e0 = 0, e1 = 0, p0 = 0, p1 = 0;
  float a0 = 0.f, a1 = 0.f;
  bool act = (n < ntok);
  if (act) {
    e0 = idx0[n]; e1 = idx1[n]; a0 = w0[n]; a1 = w1[n];
    p0 = atomicAdd(&lcnt[e0], 1);
    p1 = atomicAdd(&lcnt[e1], 1);
  }
  __syncthreads();
  if (tid < NEXP) lbase[tid] = lcnt[tid] ? atomicAdd(&cursor[tid], lcnt[tid]) : 0;
  __syncthreads();
  if (act) {
    int q0 = lbase[e0] + p0; btok[q0] = n; bw[q0] = a0; pos0[n] = q0;
    int q1 = lbase[e1] + p1; btok[q1] = n; bw[q1] = a1; pos1[n] = q1;
  }
}

// ---------------- grouped GEMM, 2-phase double-buffered ---------------------
// Tile 128x128, BK=32, 4 waves (2x2), mfma_f32_16x16x32_bf16, A&B via
// global_load_lds(16B). EO=true: store w*acc as bf16 rows of eout (no
// atomics); EO=false: atomicAdd into pre-zeroed out.
template <bool EO>
__global__ __launch_bounds__(256, 4) void k_gemm(
    const bf16t* __restrict__ xb, const bf16t* __restrict__ wT,
    const int* __restrict__ btok, const float* __restrict__ bw,
    const int* __restrict__ counts, const int* __restrict__ offs,
    const int* __restrict__ ntiles, const int* __restrict__ tlist,
    bf16t* __restrict__ eoutb, float* __restrict__ out) {
  __shared__ bf16t Asm[2][128 * 32];  // 2 x 8KB
  __shared__ bf16t Bsm[2][128 * 32];  // 2 x 8KB
  int bid = blockIdx.x;
  int t = bid >> 2, ct = bid & 3;
  if (t >= ntiles[0]) return;
  int pk = tlist[t];
  int e = pk >> 16, rt = pk & 0xffff;
  int cnt = counts[e], off = offs[e];
  int m0 = rt << 7, n0 = ct << 7;
  int tid = threadIdx.x;
  int lane = tid & 63;
  int wv = tid >> 6, wr = wv >> 1, wc = wv & 1;

  const bf16t* bsrc[2];
  const bf16t* asrcb[2];
  {
    int rr = tid >> 2, chk = tid & 3;
#pragma unroll
    for (int i = 0; i < 2; ++i) {
      bsrc[i] = wT + (size_t)(e * HDIM + n0 + i * 64 + rr) * HDIM + chk * 8;
      int gr = m0 + i * 64 + rr;
      if (gr > cnt - 1) gr = cnt - 1;  // clamp ragged tail (stores guarded)
      int tok = btok[off + gr];
      asrcb[i] = xb + (size_t)tok * HDIM + chk * 8;
    }
  }

  auto STAGE = [&](int b, int k0) {
#pragma unroll
    for (int i = 0; i < 2; ++i)
      gload_lds16(bsrc[i] + k0, &Bsm[b][i * 2048 + tid * 8]);
#pragma unroll
    for (int i = 0; i < 2; ++i)
      gload_lds16(asrcb[i] + k0, &Asm[b][i * 2048 + tid * 8]);
  };

  f32x4 acc[4][4];
#pragma unroll
  for (int a = 0; a < 4; ++a)
#pragma unroll
    for (int b = 0; b < 4; ++b) acc[a][b] = f32x4{0.f, 0.f, 0.f, 0.f};

  int aro = (wr * 64 + (lane & 15)) * 32 + (lane >> 4) * 8;
  int bro = (wc * 64 + (lane & 15)) * 32 + (lane >> 4) * 8;

  STAGE(0, 0);
  __syncthreads();  // vmcnt(0): buf0 ready
  int cur = 0;
#pragma unroll 1
  for (int kt = 0; kt < HDIM / 32; ++kt) {
    if (kt < HDIM / 32 - 1) STAGE(cur ^ 1, (kt + 1) * 32);  // prefetch next
    bf16x8 af[4], bfr[4];
#pragma unroll
    for (int mi = 0; mi < 4; ++mi)
      af[mi] = *(const bf16x8*)(&Asm[cur][aro + mi * 16 * 32]);
#pragma unroll
    for (int ni = 0; ni < 4; ++ni)
      bfr[ni] = *(const bf16x8*)(&Bsm[cur][bro + ni * 16 * 32]);
#pragma unroll
    for (int mi = 0; mi < 4; ++mi)
#pragma unroll
      for (int ni = 0; ni < 4; ++ni)
        acc[mi][ni] =
            __builtin_amdgcn_mfma_f32_16x16x32_bf16(af[mi], bfr[ni], acc[mi][ni], 0, 0, 0);
    __syncthreads();  // drains vmcnt (next stage) + lgkm (this buf's reads)
    cur ^= 1;
  }

  // Epilogue: D[row][col]: col = lane&15, row = (lane>>4)*4 + j  [m89/m91]
  int col0 = n0 + wc * 64 + (lane & 15);
  int rbase = wr * 64 + ((lane >> 4) << 2);
#pragma unroll
  for (int mi = 0; mi < 4; ++mi) {
#pragma unroll
    for (int j = 0; j < 4; ++j) {
      int rrow = m0 + rbase + mi * 16 + j;
      if (rrow < cnt) {
        float w = bw[off + rrow];
        if (EO) {
          bf16t* orow = eoutb + (size_t)(off + rrow) * HDIM + col0;
#pragma unroll
          for (int ni = 0; ni < 4; ++ni)
            orow[ni * 16] = (bf16t)(w * acc[mi][ni][j]);
        } else {
          int tok = btok[off + rrow];
          float* orow = out + (size_t)tok * HDIM + col0;
#pragma unroll
          for (int ni = 0; ni < 4; ++ni)
            atomicAdd(orow + ni * 16, w * acc[mi][ni][j]);
        }
      }
    }
  }
}

// ---------------- combine: out[n] = eout[pos0[n]] + eout[pos1[n]] -----------
__global__ void k_combine(const bf16t* __restrict__ eoutb, const int* __restrict__ pos0,
                          const int* __restrict__ pos1, float* __restrict__ out,
                          int ntok) {
  int lane = threadIdx.x & 63;
  int gw = (blockIdx.x * blockDim.x + threadIdx.x) >> 6;
  int nw = (gridDim.x * blockDim.x) >> 6;
  for (int n = gw; n < ntok; n += nw) {
    int p0 = pos0[n], p1 = pos1[n];
    bf16x8 a = *(const bf16x8*)(eoutb + (size_t)p0 * HDIM + lane * 8);
    bf16x8 b = *(const bf16x8*)(eoutb + (size_t)p1 * HDIM + lane * 8);
    float4 o0, o1;
    o0.x = (float)a[0] + (float)b[0];
    o0.y = (float)a[1] + (float)b[1];
    o0.z = (float)a[2] + (float)b[2];
    o0.w = (float)a[3] + (float)b[3];
    o1.x = (float)a[4] + (float)b[4];
    o1.y = (float)a[5] + (float)b[5];
    o1.z = (float)a[6] + (float)b[6];
    o1.w = (float)a[7] + (float)b[7];
    float4* dst = (float4*)(out + (size_t)n * HDIM + lane * 8);
    dst[0] = o0; dst[1] = o1;
  }
}

extern "C" void kernel_launch(void* const* d_in, const int* in_sizes, int n_in,
                              void* d_out, int out_size, void* d_ws, size_t ws_size,
                              hipStream_t stream) {
  const float* x = (const float*)d_in[0];
  const float* rw = (const float*)d_in[1];
  const float* W = (const float*)d_in[2];
  float* out = (float*)d_out;
  int ntok = in_sizes[0] / HDIM;  // 16384 for B=4,S=4096
  if (ntok <= 0) return;
  int maxT = ((2 * ntok + 127) >> 7) + NEXP - 1;

  // workspace layout
  char* ws = (char*)d_ws;
  size_t o = 0;
  bf16t* wT = (bf16t*)(ws + o); o += (size_t)NEXP * HDIM * HDIM * sizeof(bf16t);
  int* idx0 = (int*)(ws + o); o += (size_t)ntok * 4;
  int* idx1 = (int*)(ws + o); o += (size_t)ntok * 4;
  float* w0 = (float*)(ws + o); o += (size_t)ntok * 4;
  float* w1 = (float*)(ws + o); o += (size_t)ntok * 4;
  int* pos0 = (int*)(ws + o); o += (size_t)ntok * 4;
  int* pos1 = (int*)(ws + o); o += (size_t)ntok * 4;
  int* meta = (int*)(ws + o); o += 256;  // counts[8], offs[8], cursor[8], ntiles
  int* counts = meta;
  int* offs = meta + 8;
  int* cursor = meta + 16;
  int* ntiles = meta + 24;
  int* tlist = (int*)(ws + o); o += (size_t)((maxT * 4 + 255) & ~255);
  int* btok = (int*)(ws + o); o += (size_t)2 * ntok * 4;
  float* bw = (float*)(ws + o); o += (size_t)2 * ntok * 4;
  bf16t* xb = (bf16t*)(ws + o); o += (size_t)ntok * HDIM * sizeof(bf16t);
  size_t oXB = o;
  bf16t* eoutb = (bf16t*)(ws + o); o += (size_t)2 * ntok * HDIM * sizeof(bf16t);
  if (ws_size < oXB) return;           // ~22 MB minimum (known OK from R2)
  int useEO = (ws_size >= o) ? 1 : 0;  // +33.6 MB no-atomic path

  k_wt<<<dim3(512), dim3(256), 0, stream>>>(W, wT, counts);
  k_router<<<dim3(512), dim3(256), 0, stream>>>(x, rw, idx0, idx1, w0, w1, counts, xb,
                                                ntok);
  k_offsets<<<dim3(1), dim3(64), 0, stream>>>(counts, offs, cursor, ntiles, tlist);
  k_scatter<<<dim3((ntok + 63) / 64), dim3(64), 0, stream>>>(idx0, idx1, w0, w1, cursor,
                                                             btok, bw, pos0, pos1, ntok);
  if (useEO) {
    k_gemm<true><<<dim3(maxT * 4), dim3(256), 0, stream>>>(xb, wT, btok, bw, counts, offs,
                                                           ntiles, tlist, eoutb, out);
    k_combine<<<dim3(1024), dim3(256), 0, stream>>>(eoutb, pos0, pos1, out, ntok);
  } else {
    k_zero<<<dim3(2048), dim3(256), 0, stream>>>((float4*)out, ntok * HDIM / 4);
    k_gemm<false><<<dim3(maxT * 4), dim3(256), 0, stream>>>(xb, wT, btok, bw, counts,
                                                            offs, ntiles, tlist, eoutb,
                                                            out);
  }
}

// Round 4
// 112.711 us; speedup vs baseline: 1.4841x; 1.1210x over previous
//
#include <hip/hip_runtime.h>
#include <hip/hip_bf16.h>
#include <cstdint>
#include <cstddef>

#define HDIM 512
#define NEXP 8

typedef __bf16 bf16t;
typedef __attribute__((ext_vector_type(8))) __bf16 bf16x8;
typedef __attribute__((ext_vector_type(4))) __bf16 bf16x4;
typedef __attribute__((ext_vector_type(4))) float f32x4;

__device__ inline void gload_lds16(const void* g, void* l) {
  __builtin_amdgcn_global_load_lds(
      (const __attribute__((address_space(1))) void*)g,
      (__attribute__((address_space(3))) void*)l, 16, 0, 0);
}

// ---------------- zero output (fallback path only) ----------------
__global__ void k_zero(float4* __restrict__ p, int n4) {
  int i = blockIdx.x * blockDim.x + threadIdx.x;
  int st = gridDim.x * blockDim.x;
  for (; i < n4; i += st) p[i] = make_float4(0.f, 0.f, 0.f, 0.f);
}

// -------- W[e][h][o] f32 -> wT[e][o][h] bf16 (transpose+convert) + init ----
__global__ void k_wt(const float* __restrict__ W, bf16t* __restrict__ wT,
                     int* __restrict__ counts) {
  if (blockIdx.x == 0 && threadIdx.x < NEXP) counts[threadIdx.x] = 0;
  __shared__ float t[64][65];
  int b = blockIdx.x;
  int e = b >> 6, ht = (b >> 3) & 7, ot = b & 7;
  const float* We = W + (size_t)e * HDIM * HDIM;
  int tid = threadIdx.x;
  int c = tid & 63, rr = tid >> 6;
#pragma unroll
  for (int i = 0; i < 16; ++i) {
    int h = i * 4 + rr;
    t[h][c] = We[(size_t)(ht * 64 + h) * HDIM + ot * 64 + c];
  }
  __syncthreads();
  bf16t* dst = wT + (size_t)e * HDIM * HDIM;
#pragma unroll
  for (int i = 0; i < 16; ++i) {
    int o = i * 4 + rr;
    dst[(size_t)(ot * 64 + o) * HDIM + ht * 64 + c] = (bf16t)t[c][o];
  }
}

// ---- router: one wave per token, x read ONCE, fused x->bf16 conversion ----
// launch_bounds(256,2): 256-VGPR budget so rv[8][2] (64 VGPR) stays in regs.
__global__ __launch_bounds__(256, 2) void k_router(
    const float* __restrict__ x, const float* __restrict__ rw,
    int* __restrict__ idx0, int* __restrict__ idx1, float* __restrict__ w0,
    float* __restrict__ w1, int* __restrict__ counts, bf16t* __restrict__ xb,
    int ntok) {
  __shared__ int lcnt[NEXP];
  int tid = threadIdx.x;
  if (tid < NEXP) lcnt[tid] = 0;
  __syncthreads();
  int lane = tid & 63;
  int gw = (blockIdx.x * blockDim.x + tid) >> 6;
  int nw = (gridDim.x * blockDim.x) >> 6;
  float4 rv[NEXP][2];
#pragma unroll
  for (int e = 0; e < NEXP; ++e) {
    const float4* p = (const float4*)(rw + e * HDIM + lane * 8);
    rv[e][0] = p[0]; rv[e][1] = p[1];
  }
  for (int n = gw; n < ntok; n += nw) {
    const float4* xr = (const float4*)(x + (size_t)n * HDIM + lane * 8);
    float4 xv0 = xr[0], xv1 = xr[1];
    float a[NEXP];
#pragma unroll
    for (int e = 0; e < NEXP; ++e) {
      a[e] = xv0.x * rv[e][0].x + xv0.y * rv[e][0].y + xv0.z * rv[e][0].z +
             xv0.w * rv[e][0].w + xv1.x * rv[e][1].x + xv1.y * rv[e][1].y +
             xv1.z * rv[e][1].z + xv1.w * rv[e][1].w;
    }
    // fold reduction: same xor-1,2,4,8,16,32 tree as a per-expert butterfly,
    // but experts split across lanes (8+4+2 shfl), then 3 cross-group shfl.
    int c0 = lane & 1, c1 = (lane >> 1) & 1, c2 = (lane >> 2) & 1;
    float p0 = __shfl_xor(a[0], 1), p1 = __shfl_xor(a[1], 1);
    float p2 = __shfl_xor(a[2], 1), p3 = __shfl_xor(a[3], 1);
    float p4 = __shfl_xor(a[4], 1), p5 = __shfl_xor(a[5], 1);
    float p6 = __shfl_xor(a[6], 1), p7 = __shfl_xor(a[7], 1);
    float t0 = c0 ? a[4] + p4 : a[0] + p0;
    float t1 = c0 ? a[5] + p5 : a[1] + p1;
    float t2 = c0 ? a[6] + p6 : a[2] + p2;
    float t3 = c0 ? a[7] + p7 : a[3] + p3;
    float q0s = __shfl_xor(t0, 2), q1s = __shfl_xor(t1, 2);
    float q2s = __shfl_xor(t2, 2), q3s = __shfl_xor(t3, 2);
    float u0 = c1 ? t2 + q2s : t0 + q0s;
    float u1 = c1 ? t3 + q3s : t1 + q1s;
    float r0 = __shfl_xor(u0, 4), r1 = __shfl_xor(u1, 4);
    float wv = c2 ? u1 + r1 : u0 + r0;
    wv += __shfl_xor(wv, 8);
    wv += __shfl_xor(wv, 16);
    wv += __shfl_xor(wv, 32);
    // lane l holds expert bitrev3(l&7); gather all 8 (src = bitrev3(e))
    float lg[NEXP];
    lg[0] = __shfl(wv, 0); lg[1] = __shfl(wv, 4);
    lg[2] = __shfl(wv, 2); lg[3] = __shfl(wv, 6);
    lg[4] = __shfl(wv, 1); lg[5] = __shfl(wv, 5);
    lg[6] = __shfl(wv, 3); lg[7] = __shfl(wv, 7);
    float m = lg[0];
#pragma unroll
    for (int e = 1; e < NEXP; ++e) m = fmaxf(m, lg[e]);
    float pr[NEXP], S = 0.f;
#pragma unroll
    for (int e = 0; e < NEXP; ++e) { pr[e] = expf(lg[e] - m); S += pr[e]; }
    float inv = 1.f / S;
#pragma unroll
    for (int e = 0; e < NEXP; ++e) pr[e] *= inv;
    int b0 = 0;
#pragma unroll
    for (int e = 1; e < NEXP; ++e) if (pr[e] > pr[b0]) b0 = e;
    int b1 = (b0 == 0) ? 1 : 0;
#pragma unroll
    for (int e = 0; e < NEXP; ++e) if (e != b0 && pr[e] > pr[b1]) b1 = e;
    float v0 = pr[b0], v1 = pr[b1];
    float s = v0 + v1 + 1e-6f;
    if (lane == 0) {
      idx0[n] = b0; idx1[n] = b1;
      w0[n] = v0 / s; w1[n] = v1 / s;
      atomicAdd(&lcnt[b0], 1);
      atomicAdd(&lcnt[b1], 1);
    }
    bf16x8 h;
    h[0] = (bf16t)xv0.x; h[1] = (bf16t)xv0.y; h[2] = (bf16t)xv0.z; h[3] = (bf16t)xv0.w;
    h[4] = (bf16t)xv1.x; h[5] = (bf16t)xv1.y; h[6] = (bf16t)xv1.z; h[7] = (bf16t)xv1.w;
    *(bf16x8*)(xb + (size_t)n * HDIM + lane * 8) = h;
  }
  __syncthreads();
  if (tid < NEXP && lcnt[tid] > 0) atomicAdd(&counts[tid], lcnt[tid]);
}

// ------- offsets + exact tile list, lane-parallel ---------------------------
__global__ void k_offsets(const int* __restrict__ counts, int* __restrict__ offs,
                          int* __restrict__ cursor, int* __restrict__ ntiles,
                          int* __restrict__ tlist) {
  int lane = threadIdx.x;
  if (lane < NEXP) {
    int s = 0, tstart = 0;
    for (int i = 0; i < lane; ++i) {
      s += counts[i];
      tstart += (counts[i] + 127) >> 7;
    }
    offs[lane] = s; cursor[lane] = s;
    int rtn = (counts[lane] + 127) >> 7;
    for (int r = 0; r < rtn; ++r) tlist[tstart + r] = (lane << 16) | r;
    if (lane == NEXP - 1) ntiles[0] = tstart + rtn;
  }
}

// ---- scatter tokens into per-expert buckets; record inverse positions ----
__global__ void k_scatter(const int* __restrict__ idx0, const int* __restrict__ idx1,
                          const float* __restrict__ w0, const float* __restrict__ w1,
                          int* __restrict__ cursor, int* __restrict__ btok,
                          float* __restrict__ bw, int* __restrict__ pos0,
                          int* __restrict__ pos1, int ntok) {
  __shared__ int lcnt[NEXP], lbase[NEXP];
  int tid = threadIdx.x;
  if (tid < NEXP) lcnt[tid] = 0;
  __syncthreads();
  int n = blockIdx.x * 64 + tid;
  int e0 = 0, e1 = 0, p0 = 0, p1 = 0;
  float a0 = 0.f, a1 = 0.f;
  bool act = (n < ntok);
  if (act) {
    e0 = idx0[n]; e1 = idx1[n]; a0 = w0[n]; a1 = w1[n];
    p0 = atomicAdd(&lcnt[e0], 1);
    p1 = atomicAdd(&lcnt[e1], 1);
  }
  __syncthreads();
  if (tid < NEXP) lbase[tid] = lcnt[tid] ? atomicAdd(&cursor[tid], lcnt[tid]) : 0;
  __syncthreads();
  if (act) {
    int q0 = lbase[e0] + p0; btok[q0] = n; bw[q0] = a0; pos0[n] = q0;
    int q1 = lbase[e1] + p1; btok[q1] = n; bw[q1] = a1; pos1[n] = q1;
  }
}

// -------- grouped GEMM, 3-buffer counted-vmcnt pipeline (T4) ----------------
// Tile 128x128, BK=32, 4 waves (2x2), mfma_f32_16x16x32_bf16, A&B via
// global_load_lds(16B). Loads for K-step k+2 issued at step k; s_waitcnt
// vmcnt(8) (never 0 mid-loop) + raw s_barrier; 2nd barrier protects buffer
// reuse (buf b overwritten at step b+1 mod 3... i.e. 3-step cycle).
template <bool EO>
__global__ __launch_bounds__(256, 3) void k_gemm(
    const bf16t* __restrict__ xb, const bf16t* __restrict__ wT,
    const int* __restrict__ btok, const float* __restrict__ bw,
    const int* __restrict__ counts, const int* __restrict__ offs,
    const int* __restrict__ ntiles, const int* __restrict__ tlist,
    bf16t* __restrict__ eoutb, float* __restrict__ out) {
  __shared__ bf16t Asm[3][128 * 32];  // 3 x 8KB
  __shared__ bf16t Bsm[3][128 * 32];  // 3 x 8KB
  int bid = blockIdx.x;
  int t = bid >> 2, ct = bid & 3;
  if (t >= ntiles[0]) return;
  int pk = tlist[t];
  int e = pk >> 16, rt = pk & 0xffff;
  int cnt = counts[e], off = offs[e];
  int m0 = rt << 7, n0 = ct << 7;
  int tid = threadIdx.x;
  int lane = tid & 63;
  int wv = tid >> 6, wr = wv >> 1, wc = wv & 1;

  const bf16t* bsrc[2];
  const bf16t* asrcb[2];
  {
    int rr = tid >> 2, chk = tid & 3;
#pragma unroll
    for (int i = 0; i < 2; ++i) {
      bsrc[i] = wT + (size_t)(e * HDIM + n0 + i * 64 + rr) * HDIM + chk * 8;
      int gr = m0 + i * 64 + rr;
      if (gr > cnt - 1) gr = cnt - 1;  // clamp ragged tail (stores guarded)
      int tok = btok[off + gr];
      asrcb[i] = xb + (size_t)tok * HDIM + chk * 8;
    }
  }

  auto STAGE = [&](int b, int kt) {
    int k0 = kt * 32;
#pragma unroll
    for (int i = 0; i < 2; ++i)
      gload_lds16(bsrc[i] + k0, &Bsm[b][i * 2048 + tid * 8]);
#pragma unroll
    for (int i = 0; i < 2; ++i)
      gload_lds16(asrcb[i] + k0, &Asm[b][i * 2048 + tid * 8]);
  };

  f32x4 acc[4][4];
#pragma unroll
  for (int a = 0; a < 4; ++a)
#pragma unroll
    for (int b = 0; b < 4; ++b) acc[a][b] = f32x4{0.f, 0.f, 0.f, 0.f};

  int aro = (wr * 64 + (lane & 15)) * 32 + (lane >> 4) * 8;
  int bro = (wc * 64 + (lane & 15)) * 32 + (lane >> 4) * 8;

  constexpr int NT = HDIM / 32;  // 16
  STAGE(0, 0);
  STAGE(1, 1);
#pragma unroll
  for (int kt = 0; kt < NT; ++kt) {
    int cur = kt % 3;
    if (kt + 2 < NT) STAGE((kt + 2) % 3, kt + 2);
    int rem = NT - 1 - kt;  // stages still in flight beyond this one
    if (rem >= 2)
      asm volatile("s_waitcnt vmcnt(8)" ::: "memory");
    else if (rem == 1)
      asm volatile("s_waitcnt vmcnt(4)" ::: "memory");
    else
      asm volatile("s_waitcnt vmcnt(0)" ::: "memory");
    __builtin_amdgcn_s_barrier();          // all waves' stage-kt writes landed
    __builtin_amdgcn_sched_barrier(0);     // pin: no ds_read hoists above
    bf16x8 af[4], bfr[4];
#pragma unroll
    for (int mi = 0; mi < 4; ++mi)
      af[mi] = *(const bf16x8*)(&Asm[cur][aro + mi * 16 * 32]);
#pragma unroll
    for (int ni = 0; ni < 4; ++ni)
      bfr[ni] = *(const bf16x8*)(&Bsm[cur][bro + ni * 16 * 32]);
#pragma unroll
    for (int mi = 0; mi < 4; ++mi)
#pragma unroll
      for (int ni = 0; ni < 4; ++ni)
        acc[mi][ni] =
            __builtin_amdgcn_mfma_f32_16x16x32_bf16(af[mi], bfr[ni], acc[mi][ni], 0, 0, 0);
    __builtin_amdgcn_s_barrier();          // reads done before buf reuse
    __builtin_amdgcn_sched_barrier(0);
  }

  // Epilogue: D[row][col]: col = lane&15, row = (lane>>4)*4 + j  [m89/m91]
  int col0 = n0 + wc * 64 + (lane & 15);
  int rbase = wr * 64 + ((lane >> 4) << 2);
#pragma unroll
  for (int mi = 0; mi < 4; ++mi) {
#pragma unroll
    for (int j = 0; j < 4; ++j) {
      int rrow = m0 + rbase + mi * 16 + j;
      if (rrow < cnt) {
        float w = bw[off + rrow];
        if (EO) {
          bf16t* orow = eoutb + (size_t)(off + rrow) * HDIM + col0;
#pragma unroll
          for (int ni = 0; ni < 4; ++ni)
            orow[ni * 16] = (bf16t)(w * acc[mi][ni][j]);
        } else {
          int tok = btok[off + rrow];
          float* orow = out + (size_t)tok * HDIM + col0;
#pragma unroll
          for (int ni = 0; ni < 4; ++ni)
            atomicAdd(orow + ni * 16, w * acc[mi][ni][j]);
        }
      }
    }
  }
}

// ---------------- combine: out[n] = eout[pos0[n]] + eout[pos1[n]] -----------
__global__ void k_combine(const bf16t* __restrict__ eoutb, const int* __restrict__ pos0,
                          const int* __restrict__ pos1, float* __restrict__ out,
                          int ntok) {
  int lane = threadIdx.x & 63;
  int gw = (blockIdx.x * blockDim.x + threadIdx.x) >> 6;
  int nw = (gridDim.x * blockDim.x) >> 6;
  for (int n = gw; n < ntok; n += nw) {
    int p0 = pos0[n], p1 = pos1[n];
    bf16x8 a = *(const bf16x8*)(eoutb + (size_t)p0 * HDIM + lane * 8);
    bf16x8 b = *(const bf16x8*)(eoutb + (size_t)p1 * HDIM + lane * 8);
    float4 o0, o1;
    o0.x = (float)a[0] + (float)b[0];
    o0.y = (float)a[1] + (float)b[1];
    o0.z = (float)a[2] + (float)b[2];
    o0.w = (float)a[3] + (float)b[3];
    o1.x = (float)a[4] + (float)b[4];
    o1.y = (float)a[5] + (float)b[5];
    o1.z = (float)a[6] + (float)b[6];
    o1.w = (float)a[7] + (float)b[7];
    float4* dst = (float4*)(out + (size_t)n * HDIM + lane * 8);
    dst[0] = o0; dst[1] = o1;
  }
}

extern "C" void kernel_launch(void* const* d_in, const int* in_sizes, int n_in,
                              void* d_out, int out_size, void* d_ws, size_t ws_size,
                              hipStream_t stream) {
  const float* x = (const float*)d_in[0];
  const float* rw = (const float*)d_in[1];
  const float* W = (const float*)d_in[2];
  float* out = (float*)d_out;
  int ntok = in_sizes[0] / HDIM;  // 16384 for B=4,S=4096
  if (ntok <= 0) return;
  int maxT = ((2 * ntok + 127) >> 7) + NEXP - 1;

  // workspace layout
  char* ws = (char*)d_ws;
  size_t o = 0;
  bf16t* wT = (bf16t*)(ws + o); o += (size_t)NEXP * HDIM * HDIM * sizeof(bf16t);
  int* idx0 = (int*)(ws + o); o += (size_t)ntok * 4;
  int* idx1 = (int*)(ws + o); o += (size_t)ntok * 4;
  float* w0 = (float*)(ws + o); o += (size_t)ntok * 4;
  float* w1 = (float*)(ws + o); o += (size_t)ntok * 4;
  int* pos0 = (int*)(ws + o); o += (size_t)ntok * 4;
  int* pos1 = (int*)(ws + o); o += (size_t)ntok * 4;
  int* meta = (int*)(ws + o); o += 256;  // counts[8], offs[8], cursor[8], ntiles
  int* counts = meta;
  int* offs = meta + 8;
  int* cursor = meta + 16;
  int* ntiles = meta + 24;
  int* tlist = (int*)(ws + o); o += (size_t)((maxT * 4 + 255) & ~255);
  int* btok = (int*)(ws + o); o += (size_t)2 * ntok * 4;
  float* bw = (float*)(ws + o); o += (size_t)2 * ntok * 4;
  bf16t* xb = (bf16t*)(ws + o); o += (size_t)ntok * HDIM * sizeof(bf16t);
  size_t oXB = o;
  bf16t* eoutb = (bf16t*)(ws + o); o += (size_t)2 * ntok * HDIM * sizeof(bf16t);
  if (ws_size < oXB) return;           // ~22 MB minimum (known OK)
  int useEO = (ws_size >= o) ? 1 : 0;  // +33.6 MB no-atomic path

  k_wt<<<dim3(512), dim3(256), 0, stream>>>(W, wT, counts);
  k_router<<<dim3(512), dim3(256), 0, stream>>>(x, rw, idx0, idx1, w0, w1, counts, xb,
                                                ntok);
  k_offsets<<<dim3(1), dim3(64), 0, stream>>>(counts, offs, cursor, ntiles, tlist);
  k_scatter<<<dim3((ntok + 63) / 64), dim3(64), 0, stream>>>(idx0, idx1, w0, w1, cursor,
                                                             btok, bw, pos0, pos1, ntok);
  if (useEO) {
    k_gemm<true><<<dim3(maxT * 4), dim3(256), 0, stream>>>(xb, wT, btok, bw, counts, offs,
                                                           ntiles, tlist, eoutb, out);
    k_combine<<<dim3(1024), dim3(256), 0, stream>>>(eoutb, pos0, pos1, out, ntok);
  } else {
    k_zero<<<dim3(2048), dim3(256), 0, stream>>>((float4*)out, ntok * HDIM / 4);
    k_gemm<false><<<dim3(maxT * 4), dim3(256), 0, stream>>>(xb, wT, btok, bw, counts,
                                                            offs, ntiles, tlist, eoutb,
                                                            out);
  }
}

// Round 5
// 89.833 us; speedup vs baseline: 1.8620x; 1.2547x over previous
//
#include <hip/hip_runtime.h>
#include <hip/hip_bf16.h>
#include <cstdint>
#include <cstddef>

#define HDIM 512
#define NEXP 8

typedef __bf16 bf16t;
typedef __attribute__((ext_vector_type(8))) __bf16 bf16x8;
typedef __attribute__((ext_vector_type(4))) __bf16 bf16x4;
typedef __attribute__((ext_vector_type(4))) float f32x4;

__device__ inline void gload_lds16(const void* g, void* l) {
  __builtin_amdgcn_global_load_lds(
      (const __attribute__((address_space(1))) void*)g,
      (__attribute__((address_space(3))) void*)l, 16, 0, 0);
}

// ---------------- zero output (fallback path only) ----------------
__global__ void k_zero(float4* __restrict__ p, int n4) {
  int i = blockIdx.x * blockDim.x + threadIdx.x;
  int st = gridDim.x * blockDim.x;
  for (; i < n4; i += st) p[i] = make_float4(0.f, 0.f, 0.f, 0.f);
}

// -------- W[e][h][o] f32 -> wT[e][o][h] bf16 (transpose+convert) + init ----
__global__ void k_wt(const float* __restrict__ W, bf16t* __restrict__ wT,
                     int* __restrict__ counts) {
  if (blockIdx.x == 0 && threadIdx.x < NEXP) counts[threadIdx.x] = 0;
  __shared__ float t[64][65];
  int b = blockIdx.x;
  int e = b >> 6, ht = (b >> 3) & 7, ot = b & 7;
  const float* We = W + (size_t)e * HDIM * HDIM;
  int tid = threadIdx.x;
  int c = tid & 63, rr = tid >> 6;
#pragma unroll
  for (int i = 0; i < 16; ++i) {
    int h = i * 4 + rr;
    t[h][c] = We[(size_t)(ht * 64 + h) * HDIM + ot * 64 + c];
  }
  __syncthreads();
  bf16t* dst = wT + (size_t)e * HDIM * HDIM;
#pragma unroll
  for (int i = 0; i < 16; ++i) {
    int o = i * 4 + rr;
    dst[(size_t)(ot * 64 + o) * HDIM + ht * 64 + c] = (bf16t)t[c][o];
  }
}

__device__ inline float dot8(float4 x0, float4 x1, float4 wa, float4 wb) {
  return x0.x * wa.x + x0.y * wa.y + x0.z * wa.z + x0.w * wa.w +
         x1.x * wb.x + x1.y * wb.y + x1.z * wb.z + x1.w * wb.w;
}

// ---- router: wave/token, 4 tokens/wave prefetched, ALL-SCALAR (no allocas)
#define ROUTE_TOKEN(nn, xv0, xv1)                                              \
  if ((nn) < ntok) {                                                           \
    float s0 = dot8(xv0, xv1, r0a, r0b), s1 = dot8(xv0, xv1, r1a, r1b);        \
    float s2 = dot8(xv0, xv1, r2a, r2b), s3 = dot8(xv0, xv1, r3a, r3b);        \
    float s4 = dot8(xv0, xv1, r4a, r4b), s5 = dot8(xv0, xv1, r5a, r5b);        \
    float s6 = dot8(xv0, xv1, r6a, r6b), s7 = dot8(xv0, xv1, r7a, r7b);        \
    float p0 = __shfl_xor(s0, 1), p1 = __shfl_xor(s1, 1);                      \
    float p2 = __shfl_xor(s2, 1), p3 = __shfl_xor(s3, 1);                      \
    float p4 = __shfl_xor(s4, 1), p5 = __shfl_xor(s5, 1);                      \
    float p6 = __shfl_xor(s6, 1), p7 = __shfl_xor(s7, 1);                      \
    float t0 = c0 ? s4 + p4 : s0 + p0;                                         \
    float t1 = c0 ? s5 + p5 : s1 + p1;                                         \
    float t2 = c0 ? s6 + p6 : s2 + p2;                                         \
    float t3 = c0 ? s7 + p7 : s3 + p3;                                         \
    float q0 = __shfl_xor(t0, 2), q1 = __shfl_xor(t1, 2);                      \
    float q2 = __shfl_xor(t2, 2), q3 = __shfl_xor(t3, 2);                      \
    float u0 = c1 ? t2 + q2 : t0 + q0;                                         \
    float u1 = c1 ? t3 + q3 : t1 + q1;                                         \
    float z0 = __shfl_xor(u0, 4), z1 = __shfl_xor(u1, 4);                      \
    float wvv = c2 ? u1 + z1 : u0 + z0;                                        \
    wvv += __shfl_xor(wvv, 8);                                                 \
    wvv += __shfl_xor(wvv, 16);                                                \
    wvv += __shfl_xor(wvv, 32);                                                \
    float lg0 = __shfl(wvv, 0), lg1 = __shfl(wvv, 4);                          \
    float lg2 = __shfl(wvv, 2), lg3 = __shfl(wvv, 6);                          \
    float lg4 = __shfl(wvv, 1), lg5 = __shfl(wvv, 5);                          \
    float lg6 = __shfl(wvv, 3), lg7 = __shfl(wvv, 7);                          \
    float mm = fmaxf(fmaxf(fmaxf(lg0, lg1), fmaxf(lg2, lg3)),                  \
                     fmaxf(fmaxf(lg4, lg5), fmaxf(lg6, lg7)));                 \
    float e0 = expf(lg0 - mm), e1 = expf(lg1 - mm);                            \
    float e2 = expf(lg2 - mm), e3 = expf(lg3 - mm);                            \
    float e4 = expf(lg4 - mm), e5 = expf(lg5 - mm);                            \
    float e6 = expf(lg6 - mm), e7 = expf(lg7 - mm);                            \
    float SS = e0 + e1 + e2 + e3 + e4 + e5 + e6 + e7;                          \
    float inv = 1.f / SS;                                                      \
    e0 *= inv; e1 *= inv; e2 *= inv; e3 *= inv;                                \
    e4 *= inv; e5 *= inv; e6 *= inv; e7 *= inv;                                \
    int b0 = 0; float v0 = e0;                                                 \
    if (e1 > v0) { b0 = 1; v0 = e1; }                                          \
    if (e2 > v0) { b0 = 2; v0 = e2; }                                          \
    if (e3 > v0) { b0 = 3; v0 = e3; }                                          \
    if (e4 > v0) { b0 = 4; v0 = e4; }                                          \
    if (e5 > v0) { b0 = 5; v0 = e5; }                                          \
    if (e6 > v0) { b0 = 6; v0 = e6; }                                          \
    if (e7 > v0) { b0 = 7; v0 = e7; }                                          \
    int b1 = -1; float v1 = -1.f;                                              \
    if (b0 != 0) { b1 = 0; v1 = e0; }                                          \
    if (b0 != 1 && e1 > v1) { b1 = 1; v1 = e1; }                               \
    if (b0 != 2 && e2 > v1) { b1 = 2; v1 = e2; }                               \
    if (b0 != 3 && e3 > v1) { b1 = 3; v1 = e3; }                               \
    if (b0 != 4 && e4 > v1) { b1 = 4; v1 = e4; }                               \
    if (b0 != 5 && e5 > v1) { b1 = 5; v1 = e5; }                               \
    if (b0 != 6 && e6 > v1) { b1 = 6; v1 = e6; }                               \
    if (b0 != 7 && e7 > v1) { b1 = 7; v1 = e7; }                               \
    float ssum = v0 + v1 + 1e-6f;                                              \
    if (lane == 0) {                                                           \
      idx0[nn] = b0; idx1[nn] = b1;                                            \
      w0[nn] = v0 / ssum; w1[nn] = v1 / ssum;                                  \
      atomicAdd(&lcnt[b0], 1); atomicAdd(&lcnt[b1], 1);                        \
    }                                                                          \
    bf16x8 hh;                                                                 \
    hh[0] = (bf16t)xv0.x; hh[1] = (bf16t)xv0.y;                                \
    hh[2] = (bf16t)xv0.z; hh[3] = (bf16t)xv0.w;                                \
    hh[4] = (bf16t)xv1.x; hh[5] = (bf16t)xv1.y;                                \
    hh[6] = (bf16t)xv1.z; hh[7] = (bf16t)xv1.w;                                \
    *(bf16x8*)(xb + (size_t)(nn)*HDIM + lane * 8) = hh;                        \
  }

__global__ __launch_bounds__(256, 2) void k_router(
    const float* __restrict__ x, const float* __restrict__ rw,
    int* __restrict__ idx0, int* __restrict__ idx1, float* __restrict__ w0,
    float* __restrict__ w1, int* __restrict__ counts, bf16t* __restrict__ xb,
    int ntok) {
  __shared__ int lcnt[NEXP];
  int tid = threadIdx.x;
  if (tid < NEXP) lcnt[tid] = 0;
  __syncthreads();
  int lane = tid & 63;
  int c0 = lane & 1, c1 = (lane >> 1) & 1, c2 = (lane >> 2) & 1;
  int l2 = lane * 2;
  const float4* rwp = (const float4*)rw;  // rw[e][lane*8..] -> rwp[e*128+l2]
  float4 r0a = rwp[0 * 128 + l2], r0b = rwp[0 * 128 + l2 + 1];
  float4 r1a = rwp[1 * 128 + l2], r1b = rwp[1 * 128 + l2 + 1];
  float4 r2a = rwp[2 * 128 + l2], r2b = rwp[2 * 128 + l2 + 1];
  float4 r3a = rwp[3 * 128 + l2], r3b = rwp[3 * 128 + l2 + 1];
  float4 r4a = rwp[4 * 128 + l2], r4b = rwp[4 * 128 + l2 + 1];
  float4 r5a = rwp[5 * 128 + l2], r5b = rwp[5 * 128 + l2 + 1];
  float4 r6a = rwp[6 * 128 + l2], r6b = rwp[6 * 128 + l2 + 1];
  float4 r7a = rwp[7 * 128 + l2], r7b = rwp[7 * 128 + l2 + 1];
  int gwave = blockIdx.x * 4 + (tid >> 6);
  int nb = gwave * 4;  // 4 tokens per wave
  const float4* xp = (const float4*)x;
  int lastn = ntok - 1;
  int i0 = nb + 0 > lastn ? lastn : nb + 0;
  int i1 = nb + 1 > lastn ? lastn : nb + 1;
  int i2 = nb + 2 > lastn ? lastn : nb + 2;
  int i3 = nb + 3 > lastn ? lastn : nb + 3;
  // all 8 x loads issued up-front (prefetch; ~8KB in flight per wave)
  float4 x0a = xp[(size_t)i0 * 128 + l2], x0b = xp[(size_t)i0 * 128 + l2 + 1];
  float4 x1a = xp[(size_t)i1 * 128 + l2], x1b = xp[(size_t)i1 * 128 + l2 + 1];
  float4 x2a = xp[(size_t)i2 * 128 + l2], x2b = xp[(size_t)i2 * 128 + l2 + 1];
  float4 x3a = xp[(size_t)i3 * 128 + l2], x3b = xp[(size_t)i3 * 128 + l2 + 1];
  ROUTE_TOKEN(nb + 0, x0a, x0b)
  ROUTE_TOKEN(nb + 1, x1a, x1b)
  ROUTE_TOKEN(nb + 2, x2a, x2b)
  ROUTE_TOKEN(nb + 3, x3a, x3b)
  __syncthreads();
  if (tid < NEXP && lcnt[tid] > 0) atomicAdd(&counts[tid], lcnt[tid]);
}

// ------- offsets + exact tile list, lane-parallel ---------------------------
__global__ void k_offsets(const int* __restrict__ counts, int* __restrict__ offs,
                          int* __restrict__ cursor, int* __restrict__ ntiles,
                          int* __restrict__ tlist) {
  int lane = threadIdx.x;
  if (lane < NEXP) {
    int s = 0, tstart = 0;
    for (int i = 0; i < lane; ++i) {
      s += counts[i];
      tstart += (counts[i] + 127) >> 7;
    }
    offs[lane] = s; cursor[lane] = s;
    int rtn = (counts[lane] + 127) >> 7;
    for (int r = 0; r < rtn; ++r) tlist[tstart + r] = (lane << 16) | r;
    if (lane == NEXP - 1) ntiles[0] = tstart + rtn;
  }
}

// ---- scatter tokens into per-expert buckets; record inverse positions ----
__global__ void k_scatter(const int* __restrict__ idx0, const int* __restrict__ idx1,
                          const float* __restrict__ w0, const float* __restrict__ w1,
                          int* __restrict__ cursor, int* __restrict__ btok,
                          float* __restrict__ bw, int* __restrict__ pos0,
                          int* __restrict__ pos1, int ntok) {
  __shared__ int lcnt[NEXP], lbase[NEXP];
  int tid = threadIdx.x;
  if (tid < NEXP) lcnt[tid] = 0;
  __syncthreads();
  int n = blockIdx.x * 64 + tid;
  int e0 = 0, e1 = 0, p0 = 0, p1 = 0;
  float a0 = 0.f, a1 = 0.f;
  bool act = (n < ntok);
  if (act) {
    e0 = idx0[n]; e1 = idx1[n]; a0 = w0[n]; a1 = w1[n];
    p0 = atomicAdd(&lcnt[e0], 1);
    p1 = atomicAdd(&lcnt[e1], 1);
  }
  __syncthreads();
  if (tid < NEXP) lbase[tid] = lcnt[tid] ? atomicAdd(&cursor[tid], lcnt[tid]) : 0;
  __syncthreads();
  if (act) {
    int q0 = lbase[e0] + p0; btok[q0] = n; bw[q0] = a0; pos0[n] = q0;
    int q1 = lbase[e1] + p1; btok[q1] = n; bw[q1] = a1; pos1[n] = q1;
  }
}

// -------- grouped GEMM, 3-buffer counted-vmcnt pipeline (T4) ----------------
template <bool EO>
__global__ __launch_bounds__(256, 3) void k_gemm(
    const bf16t* __restrict__ xb, const bf16t* __restrict__ wT,
    const int* __restrict__ btok, const float* __restrict__ bw,
    const int* __restrict__ counts, const int* __restrict__ offs,
    const int* __restrict__ ntiles, const int* __restrict__ tlist,
    bf16t* __restrict__ eoutb, float* __restrict__ out) {
  __shared__ bf16t Asm[3][128 * 32];  // 3 x 8KB
  __shared__ bf16t Bsm[3][128 * 32];  // 3 x 8KB
  int bid = blockIdx.x;
  int t = bid >> 2, ct = bid & 3;
  if (t >= ntiles[0]) return;
  int pk = tlist[t];
  int e = pk >> 16, rt = pk & 0xffff;
  int cnt = counts[e], off = offs[e];
  int m0 = rt << 7, n0 = ct << 7;
  int tid = threadIdx.x;
  int lane = tid & 63;
  int wv = tid >> 6, wr = wv >> 1, wc = wv & 1;

  const bf16t* bsrc[2];
  const bf16t* asrcb[2];
  {
    int rr = tid >> 2, chk = tid & 3;
#pragma unroll
    for (int i = 0; i < 2; ++i) {
      bsrc[i] = wT + (size_t)(e * HDIM + n0 + i * 64 + rr) * HDIM + chk * 8;
      int gr = m0 + i * 64 + rr;
      if (gr > cnt - 1) gr = cnt - 1;  // clamp ragged tail (stores guarded)
      int tok = btok[off + gr];
      asrcb[i] = xb + (size_t)tok * HDIM + chk * 8;
    }
  }

  auto STAGE = [&](int b, int kt) {
    int k0 = kt * 32;
#pragma unroll
    for (int i = 0; i < 2; ++i)
      gload_lds16(bsrc[i] + k0, &Bsm[b][i * 2048 + tid * 8]);
#pragma unroll
    for (int i = 0; i < 2; ++i)
      gload_lds16(asrcb[i] + k0, &Asm[b][i * 2048 + tid * 8]);
  };

  f32x4 acc[4][4];
#pragma unroll
  for (int a = 0; a < 4; ++a)
#pragma unroll
    for (int b = 0; b < 4; ++b) acc[a][b] = f32x4{0.f, 0.f, 0.f, 0.f};

  int aro = (wr * 64 + (lane & 15)) * 32 + (lane >> 4) * 8;
  int bro = (wc * 64 + (lane & 15)) * 32 + (lane >> 4) * 8;

  constexpr int NT = HDIM / 32;  // 16
  STAGE(0, 0);
  STAGE(1, 1);
#pragma unroll
  for (int kt = 0; kt < NT; ++kt) {
    int cur = kt % 3;
    if (kt + 2 < NT) STAGE((kt + 2) % 3, kt + 2);
    int rem = NT - 1 - kt;
    if (rem >= 2)
      asm volatile("s_waitcnt vmcnt(8)" ::: "memory");
    else if (rem == 1)
      asm volatile("s_waitcnt vmcnt(4)" ::: "memory");
    else
      asm volatile("s_waitcnt vmcnt(0)" ::: "memory");
    __builtin_amdgcn_s_barrier();
    __builtin_amdgcn_sched_barrier(0);
    bf16x8 af[4], bfr[4];
#pragma unroll
    for (int mi = 0; mi < 4; ++mi)
      af[mi] = *(const bf16x8*)(&Asm[cur][aro + mi * 16 * 32]);
#pragma unroll
    for (int ni = 0; ni < 4; ++ni)
      bfr[ni] = *(const bf16x8*)(&Bsm[cur][bro + ni * 16 * 32]);
#pragma unroll
    for (int mi = 0; mi < 4; ++mi)
#pragma unroll
      for (int ni = 0; ni < 4; ++ni)
        acc[mi][ni] =
            __builtin_amdgcn_mfma_f32_16x16x32_bf16(af[mi], bfr[ni], acc[mi][ni], 0, 0, 0);
    __builtin_amdgcn_s_barrier();
    __builtin_amdgcn_sched_barrier(0);
  }

  int col0 = n0 + wc * 64 + (lane & 15);
  int rbase = wr * 64 + ((lane >> 4) << 2);
#pragma unroll
  for (int mi = 0; mi < 4; ++mi) {
#pragma unroll
    for (int j = 0; j < 4; ++j) {
      int rrow = m0 + rbase + mi * 16 + j;
      if (rrow < cnt) {
        float w = bw[off + rrow];
        if (EO) {
          bf16t* orow = eoutb + (size_t)(off + rrow) * HDIM + col0;
#pragma unroll
          for (int ni = 0; ni < 4; ++ni)
            orow[ni * 16] = (bf16t)(w * acc[mi][ni][j]);
        } else {
          int tok = btok[off + rrow];
          float* orow = out + (size_t)tok * HDIM + col0;
#pragma unroll
          for (int ni = 0; ni < 4; ++ni)
            atomicAdd(orow + ni * 16, w * acc[mi][ni][j]);
        }
      }
    }
  }
}

// ---------------- combine: out[n] = eout[pos0[n]] + eout[pos1[n]] -----------
__global__ void k_combine(const bf16t* __restrict__ eoutb, const int* __restrict__ pos0,
                          const int* __restrict__ pos1, float* __restrict__ out,
                          int ntok) {
  int lane = threadIdx.x & 63;
  int gw = (blockIdx.x * blockDim.x + threadIdx.x) >> 6;
  int nw = (gridDim.x * blockDim.x) >> 6;
  for (int n = gw; n < ntok; n += nw) {
    int p0 = pos0[n], p1 = pos1[n];
    bf16x8 a = *(const bf16x8*)(eoutb + (size_t)p0 * HDIM + lane * 8);
    bf16x8 b = *(const bf16x8*)(eoutb + (size_t)p1 * HDIM + lane * 8);
    float4 o0, o1;
    o0.x = (float)a[0] + (float)b[0];
    o0.y = (float)a[1] + (float)b[1];
    o0.z = (float)a[2] + (float)b[2];
    o0.w = (float)a[3] + (float)b[3];
    o1.x = (float)a[4] + (float)b[4];
    o1.y = (float)a[5] + (float)b[5];
    o1.z = (float)a[6] + (float)b[6];
    o1.w = (float)a[7] + (float)b[7];
    float4* dst = (float4*)(out + (size_t)n * HDIM + lane * 8);
    dst[0] = o0; dst[1] = o1;
  }
}

extern "C" void kernel_launch(void* const* d_in, const int* in_sizes, int n_in,
                              void* d_out, int out_size, void* d_ws, size_t ws_size,
                              hipStream_t stream) {
  const float* x = (const float*)d_in[0];
  const float* rw = (const float*)d_in[1];
  const float* W = (const float*)d_in[2];
  float* out = (float*)d_out;
  int ntok = in_sizes[0] / HDIM;  // 16384 for B=4,S=4096
  if (ntok <= 0) return;
  int maxT = ((2 * ntok + 127) >> 7) + NEXP - 1;

  // workspace layout
  char* ws = (char*)d_ws;
  size_t o = 0;
  bf16t* wT = (bf16t*)(ws + o); o += (size_t)NEXP * HDIM * HDIM * sizeof(bf16t);
  int* idx0 = (int*)(ws + o); o += (size_t)ntok * 4;
  int* idx1 = (int*)(ws + o); o += (size_t)ntok * 4;
  float* w0 = (float*)(ws + o); o += (size_t)ntok * 4;
  float* w1 = (float*)(ws + o); o += (size_t)ntok * 4;
  int* pos0 = (int*)(ws + o); o += (size_t)ntok * 4;
  int* pos1 = (int*)(ws + o); o += (size_t)ntok * 4;
  int* meta = (int*)(ws + o); o += 256;  // counts[8], offs[8], cursor[8], ntiles
  int* counts = meta;
  int* offs = meta + 8;
  int* cursor = meta + 16;
  int* ntiles = meta + 24;
  int* tlist = (int*)(ws + o); o += (size_t)((maxT * 4 + 255) & ~255);
  int* btok = (int*)(ws + o); o += (size_t)2 * ntok * 4;
  float* bw = (float*)(ws + o); o += (size_t)2 * ntok * 4;
  bf16t* xb = (bf16t*)(ws + o); o += (size_t)ntok * HDIM * sizeof(bf16t);
  size_t oXB = o;
  bf16t* eoutb = (bf16t*)(ws + o); o += (size_t)2 * ntok * HDIM * sizeof(bf16t);
  if (ws_size < oXB) return;           // ~22 MB minimum (known OK)
  int useEO = (ws_size >= o) ? 1 : 0;  // +33.6 MB no-atomic path

  k_wt<<<dim3(512), dim3(256), 0, stream>>>(W, wT, counts);
  k_router<<<dim3((ntok + 15) / 16), dim3(256), 0, stream>>>(x, rw, idx0, idx1, w0, w1,
                                                             counts, xb, ntok);
  k_offsets<<<dim3(1), dim3(64), 0, stream>>>(counts, offs, cursor, ntiles, tlist);
  k_scatter<<<dim3((ntok + 63) / 64), dim3(64), 0, stream>>>(idx0, idx1, w0, w1, cursor,
                                                             btok, bw, pos0, pos1, ntok);
  if (useEO) {
    k_gemm<true><<<dim3(maxT * 4), dim3(256), 0, stream>>>(xb, wT, btok, bw, counts, offs,
                                                           ntiles, tlist, eoutb, out);
    k_combine<<<dim3(1024), dim3(256), 0, stream>>>(eoutb, pos0, pos1, out, ntok);
  } else {
    k_zero<<<dim3(2048), dim3(256), 0, stream>>>((float4*)out, ntok * HDIM / 4);
    k_gemm<false><<<dim3(maxT * 4), dim3(256), 0, stream>>>(xb, wT, btok, bw, counts,
                                                            offs, ntiles, tlist, eoutb,
                                                            out);
  }
}